// Round 1
// baseline (41.016 us; speedup 1.0000x reference)
//
#include <hip/hip_runtime.h>
#include <hip/hip_bf16.h>

// CosSim2D (K=3, same-pad, C=32 -> F=32) on MI355X.
// Strategy: im2col-on-the-fly bf16 MFMA GEMM (M=pixels, K=288, N=32),
// fp32 norms via per-pixel sum-of-squares + 3x3 window sum.
// B (w/wnorm) is pre-swizzled into mfma_f32_32x32x16_bf16 B-fragment order.

#define H_ 224
#define W_ 224
#define C_ 32
#define F_ 32
#define B_ 8

typedef __bf16 bf16_t;
typedef bf16_t bf16x8 __attribute__((ext_vector_type(8)));
typedef float f32x16 __attribute__((ext_vector_type(16)));

#define NSTEP 18                        // K = 288 = 18 * 16
#define WFRAG_BYTES (NSTEP * 64 * 8 * 2)  // 18432 B of bf16 fragments

// ---------------- prep: w-norm fold + fragment swizzle + exponents ----------
__global__ __launch_bounds__(256) void cos2d_prep(
    const float* __restrict__ w, const float* __restrict__ p,
    const float* __restrict__ q, bf16_t* __restrict__ wfrag,
    float* __restrict__ ef) {
  __shared__ float winv[F_];
  const int tid = threadIdx.x;
  const float qt = q[0] * q[0] * 0.1f;
  if (tid < F_) {
    float s = 0.f;
    for (int k = 0; k < 288; ++k) { float v = w[k * F_ + tid]; s += v * v; }
    winv[tid] = 1.f / (sqrtf(fmaxf(s, 1e-12f)) + qt);
    ef[tid] = p[tid] * p[tid] * 0.01f;
  }
  __syncthreads();
  // B-fragment layout assumed for mfma_f32_32x32x16_bf16:
  //   lane l holds col f = l&31, k = (l>>5)*8 + e  (e = 0..7), per 16-k step s2.
  for (int t = tid; t < NSTEP * 64; t += 256) {
    const int s2 = t >> 6, l = t & 63;
    const int f = l & 31;
    const float wi = winv[f];
    union { bf16_t v[8]; uint4 u; } tv;
#pragma unroll
    for (int e = 0; e < 8; ++e) {
      const int kk = s2 * 16 + ((l >> 5) << 3) + e;   // absolute k in [0,288)
      tv.v[e] = (bf16_t)(w[kk * F_ + f] * wi);
    }
    *(uint4*)(wfrag + (size_t)t * 8) = tv.u;
  }
}

// ---------------- main ------------------------------------------------------
// Block: 256 thr (4 waves). Tile: 8 rows x 32 cols of one image.
// Grid: 8 * 28 * 7 = 1568 blocks (exact fit).
__global__ __launch_bounds__(256) void cos2d_main(
    const float* __restrict__ img, const bf16_t* __restrict__ wfrag,
    const float* __restrict__ ef, const float* __restrict__ q,
    float* __restrict__ out) {
  // stride 40 bf16 = 80 B per staged pixel row: 16B-aligned, 20-bank stride
  // -> wave64 ds_read_b128 achieves full LDS BW (8 lanes cover all 32 banks).
  __shared__ bf16_t xt[10][34][40];
  __shared__ float ssum[10][34];

  const int tid = threadIdx.x;
  const int bid = blockIdx.x;
  const int tw = bid % 7;
  const int th = (bid / 7) % 28;
  const int b  = bid / (7 * 28);
  const int h0 = th * 8, w0 = tw * 32;

  const float qt = q[0] * q[0] * 0.1f;
  const int lane = tid & 63;
  const int wv = tid >> 6;
  const int lp = lane & 31;

  // B fragments for all 18 k-steps (held in VGPRs across both M-tiles)
  bf16x8 bfrag[NSTEP];
  const bf16x8* wf4 = (const bf16x8*)wfrag;
#pragma unroll
  for (int s2 = 0; s2 < NSTEP; ++s2) bfrag[s2] = wf4[s2 * 64 + lane];

  // ---- stage halo tile (rows h0-1..h0+8, cols w0-1..w0+32) as bf16 + fp32 s
  for (int idx = tid; idx < 340; idx += 256) {
    const int rr = idx / 34, cc = idx - rr * 34;
    const int hh = h0 - 1 + rr, wc = w0 - 1 + cc;
    float s = 0.f;
    union { bf16_t v[32]; uint4 u[4]; } tv;
    if (hh >= 0 && hh < H_ && wc >= 0 && wc < W_) {
      const float4* p4 =
          (const float4*)(img + (size_t)((b * H_ + hh) * W_ + wc) * C_);
#pragma unroll
      for (int j = 0; j < 8; ++j) {
        const float4 v = p4[j];
        s += v.x * v.x + v.y * v.y + v.z * v.z + v.w * v.w;
        tv.v[4 * j + 0] = (bf16_t)v.x;
        tv.v[4 * j + 1] = (bf16_t)v.y;
        tv.v[4 * j + 2] = (bf16_t)v.z;
        tv.v[4 * j + 3] = (bf16_t)v.w;
      }
    } else {
#pragma unroll
      for (int j = 0; j < 4; ++j) tv.u[j] = make_uint4(0u, 0u, 0u, 0u);
    }
    ssum[rr][cc] = s;
    uint4* dst = (uint4*)&xt[rr][cc][0];
#pragma unroll
    for (int j = 0; j < 4; ++j) dst[j] = tv.u[j];
  }
  __syncthreads();

  const float efv = ef[lp];

#pragma unroll
  for (int t = 0; t < 2; ++t) {
    const int mr = wv * 2 + t;  // M-tile = image row (h0+mr), 32 w-columns

    // x_norm^2 = 3x3 window sum of per-pixel channel sum-of-squares
    const float xn2 = ssum[mr + 0][lp] + ssum[mr + 0][lp + 1] + ssum[mr + 0][lp + 2]
                    + ssum[mr + 1][lp] + ssum[mr + 1][lp + 1] + ssum[mr + 1][lp + 2]
                    + ssum[mr + 2][lp] + ssum[mr + 2][lp + 1] + ssum[mr + 2][lp + 2];
    const float xinv = 1.f / (sqrtf(fmaxf(xn2, 1e-12f)) + qt);

    f32x16 acc;
#pragma unroll
    for (int i = 0; i < 16; ++i) acc[i] = 0.f;

    // K loop: 18 steps of 16. A-fragment (assumed): lane l -> row = l&31
    // (pixel col), k = (l>>5)*8 + e -> 8 contiguous channels from LDS.
#pragma unroll
    for (int s2 = 0; s2 < NSTEP; ++s2) {
      const int pos = s2 >> 1;
      const int dy = pos / 3, dx = pos - dy * 3;
      const int chof = (s2 & 1) * 16 + ((lane >> 5) << 3);
      const bf16x8 af = *(const bf16x8*)&xt[mr + dy][lp + dx][chof];
      acc = __builtin_amdgcn_mfma_f32_32x32x16_bf16(af, bfrag[s2], acc, 0, 0, 0);
    }

    // epilogue: C/D layout (guide-verified): col = lane&31,
    // row = (reg&3) + 8*(reg>>2) + 4*(lane>>5)
    const int obase = (b * H_ + h0 + mr) * W_ + w0;
#pragma unroll
    for (int j = 0; j < 16; ++j) {
      const int row = (j & 3) + 8 * (j >> 2) + 4 * (lane >> 5);
      const float xi = __shfl(xinv, row);
      const float sim = acc[j] * xi;
      const float ps = fabsf(sim) + 1e-12f;
      float r = exp2f(efv * __log2f(ps));
      r = copysignf(r, sim);
      out[(size_t)(obase + row) * F_ + lp] = r;
    }
  }
}

// ---------------- launch ----------------------------------------------------
extern "C" void kernel_launch(void* const* d_in, const int* in_sizes, int n_in,
                              void* d_out, int out_size, void* d_ws, size_t ws_size,
                              hipStream_t stream) {
  const float* img = (const float*)d_in[0];
  const float* w   = (const float*)d_in[1];
  const float* p   = (const float*)d_in[2];
  const float* q   = (const float*)d_in[3];

  bf16_t* wfrag = (bf16_t*)d_ws;
  float*  ef    = (float*)((char*)d_ws + WFRAG_BYTES);

  cos2d_prep<<<1, 256, 0, stream>>>(w, p, q, wfrag, ef);
  cos2d_main<<<1568, 256, 0, stream>>>(img, wfrag, ef, q, (float*)d_out);
}

// Round 2
// 40.165 us; speedup vs baseline: 1.0212x; 1.0212x over previous
//
#include <hip/hip_runtime.h>
#include <hip/hip_bf16.h>

// CosSim2D (K=3, same-pad, C=32 -> F=32) on MI355X — fused single kernel.
// im2col-on-the-fly bf16 MFMA GEMM (M=pixels, K=288, N=32).
// - w-norm computed per block by wave 0 (w is tiny & L2-resident), applied in
//   fp32 epilogue (NOT folded into bf16 w) -> no staging dependency.
// - B fragments staged to LDS in mfma_f32_32x32x16_bf16 B-layout, read in-loop
//   (keeps VGPR ~100 -> 4 waves/SIMD; LDS allows 2 blocks/CU = 16 waves/CU).
// - 16x32 output tile per block (halo 18x34, overfetch 1.20x).

#define H_ 224
#define W_ 224
#define C_ 32
#define F_ 32

#define NSTEP 18   // K = 288 = 18 * 16
#define TROWS 16   // output rows per block
#define HROWS 18   // staged halo rows
#define HCOLS 34   // staged halo cols

typedef __bf16 bf16_t;
typedef bf16_t bf16x8 __attribute__((ext_vector_type(8)));
typedef float f32x16 __attribute__((ext_vector_type(16)));

__global__ __launch_bounds__(512, 4) void cos2d_fused(
    const float* __restrict__ img, const float* __restrict__ w,
    const float* __restrict__ p, const float* __restrict__ q,
    float* __restrict__ out) {
  // stride 40 bf16 = 80 B per staged pixel: 16B-aligned, 20-bank stride ->
  // wave64 ds_read/write_b128 covers all 32 banks (2-way = free).
  __shared__ bf16_t xt[HROWS][HCOLS][40];
  __shared__ float ssum[HROWS][HCOLS];
  __shared__ bf16_t wfrag[NSTEP][64][8];  // B-fragment layout per 16-k step
  __shared__ float winv_s[F_];

  const int tid = threadIdx.x;
  const int lane = tid & 63;
  const int wv = tid >> 6;
  const int lp = lane & 31;

  const int bid = blockIdx.x;
  const int tw = bid % 7;
  const int th = (bid / 7) % 14;
  const int b  = bid / 98;
  const int h0 = th * TROWS, w0 = tw * 32;

  const float qt = q[0] * q[0] * 0.1f;
  const float efv = p[lp] * p[lp] * 0.01f;

  // ---- wave 0: per-filter weight norm (redundant per block; w is L2-hot)
  if (wv == 0) {
    const int j = lane >> 5, f = lane & 31;
    float s0 = 0.f, s1 = 0.f, s2 = 0.f, s3 = 0.f;
#pragma unroll 4
    for (int i = 0; i < 144; i += 4) {
      const float v0 = w[(2 * (i + 0) + j) * F_ + f];
      const float v1 = w[(2 * (i + 1) + j) * F_ + f];
      const float v2 = w[(2 * (i + 2) + j) * F_ + f];
      const float v3 = w[(2 * (i + 3) + j) * F_ + f];
      s0 += v0 * v0; s1 += v1 * v1; s2 += v2 * v2; s3 += v3 * v3;
    }
    float s = (s0 + s1) + (s2 + s3);
    s += __shfl_xor(s, 32);
    if (lane < 32) winv_s[f] = 1.f / (sqrtf(fmaxf(s, 1e-12f)) + qt);
  }

  // ---- all threads: stage bf16 w into B-fragment LDS layout.
  // Element (kk, f) lives at wfrag[kk/16][ (f + 32*((kk%16)/8)) ][ kk%8 ].
  // Thread mapping chosen so LDS writes are pid-linear (conflict-free b32).
  {
    const int pid = tid & 255;
    const int f  = (pid >> 2) & 31;
    const int hi = pid >> 7;        // ((pid>>2)>>5)
    const int ep = pid & 3;
    char* const wbase = (char*)&wfrag[0][0][0];
    for (int r2 = tid >> 8; r2 < NSTEP; r2 += 2) {
      const int kk = r2 * 16 + hi * 8 + 2 * ep;
      const float v0 = w[kk * F_ + f];
      const float v1 = w[(kk + 1) * F_ + f];
      union { bf16_t h[2]; unsigned u; } pr;
      pr.h[0] = (bf16_t)v0;
      pr.h[1] = (bf16_t)v1;
      *(unsigned*)(wbase + r2 * 1024 + pid * 4) = pr.u;
    }
  }

  // ---- stage image halo tile (rows h0-1..h0+16, cols w0-1..w0+32)
  for (int idx = tid; idx < HROWS * HCOLS; idx += 512) {
    const int rr = idx / HCOLS, cc = idx - rr * HCOLS;
    const int hh = h0 - 1 + rr, wc = w0 - 1 + cc;
    float s = 0.f;
    union { bf16_t v[32]; uint4 u[4]; } tv;
    if ((unsigned)hh < H_ && (unsigned)wc < W_) {
      const float4* p4 =
          (const float4*)(img + ((size_t)(b * H_ + hh) * W_ + wc) * C_);
#pragma unroll
      for (int jj = 0; jj < 8; ++jj) {
        const float4 v = p4[jj];
        s += v.x * v.x + v.y * v.y + v.z * v.z + v.w * v.w;
        tv.v[4 * jj + 0] = (bf16_t)v.x;
        tv.v[4 * jj + 1] = (bf16_t)v.y;
        tv.v[4 * jj + 2] = (bf16_t)v.z;
        tv.v[4 * jj + 3] = (bf16_t)v.w;
      }
    } else {
#pragma unroll
      for (int jj = 0; jj < 4; ++jj) tv.u[jj] = make_uint4(0u, 0u, 0u, 0u);
    }
    ssum[rr][cc] = s;
    uint4* dst = (uint4*)&xt[rr][cc][0];
#pragma unroll
    for (int jj = 0; jj < 4; ++jj) dst[jj] = tv.u[jj];
  }
  __syncthreads();

  const float wnv = winv_s[lp];  // per-filter 1/(||w||+qt), filter = lp

#pragma unroll
  for (int t = 0; t < 2; ++t) {
    const int mr = wv * 2 + t;  // output row (tile-relative); cols = lp

    // x_norm: 3x3 window sum of per-pixel channel sum-of-squares (fp32 exact)
    const float xn2 = ssum[mr + 0][lp] + ssum[mr + 0][lp + 1] + ssum[mr + 0][lp + 2]
                    + ssum[mr + 1][lp] + ssum[mr + 1][lp + 1] + ssum[mr + 1][lp + 2]
                    + ssum[mr + 2][lp] + ssum[mr + 2][lp + 1] + ssum[mr + 2][lp + 2];
    const float xinv = 1.f / (sqrtf(fmaxf(xn2, 1e-12f)) + qt);

    f32x16 acc;
#pragma unroll
    for (int i = 0; i < 16; ++i) acc[i] = 0.f;

    // K loop: A lane l -> pixel col = l&31, k = (l>>5)*8+e (8 contig channels)
#pragma unroll
    for (int s2 = 0; s2 < NSTEP; ++s2) {
      const int pos = s2 >> 1;
      const int dy = pos / 3, dx = pos - dy * 3;
      const int chof = (s2 & 1) * 16 + ((lane >> 5) << 3);
      const bf16x8 af = *(const bf16x8*)&xt[mr + dy][lp + dx][chof];
      const bf16x8 bf = *(const bf16x8*)&wfrag[s2][lane][0];
      acc = __builtin_amdgcn_mfma_f32_32x32x16_bf16(af, bf, acc, 0, 0, 0);
    }

    // epilogue: C/D layout col = lane&31 (filter), row = (j&3)+8*(j>>2)+4*(lane>>5)
    const int obase = (b * H_ + h0 + mr) * W_ + w0;
#pragma unroll
    for (int jj = 0; jj < 16; ++jj) {
      const int row = (jj & 3) + 8 * (jj >> 2) + 4 * (lane >> 5);
      const float xi = __shfl(xinv, row);   // xinv of pixel-col `row`
      const float sim = acc[jj] * xi * wnv;
      const float ps = fabsf(sim) + 1e-12f;
      float r = exp2f(efv * __log2f(ps));
      r = copysignf(r, sim);
      out[(size_t)(obase + row) * F_ + lp] = r;
    }
  }
}

// ---------------- launch ----------------------------------------------------
extern "C" void kernel_launch(void* const* d_in, const int* in_sizes, int n_in,
                              void* d_out, int out_size, void* d_ws, size_t ws_size,
                              hipStream_t stream) {
  const float* img = (const float*)d_in[0];
  const float* w   = (const float*)d_in[1];
  const float* p   = (const float*)d_in[2];
  const float* q   = (const float*)d_in[3];
  // 8 images * 14 row-tiles * 7 col-tiles = 784 blocks, 512 threads (8 waves)
  cos2d_fused<<<784, 512, 0, stream>>>(img, w, p, q, (float*)d_out);
}

// Round 3
// 35.895 us; speedup vs baseline: 1.1427x; 1.1190x over previous
//
#include <hip/hip_runtime.h>
#include <hip/hip_bf16.h>

// CosSim2D (K=3, same-pad, C=32 -> F=32) on MI355X.
// im2col-on-the-fly bf16 MFMA GEMM (M=pixels, K=288, N=32).
// Round 3: occupancy-focused split.
//  - prep kernel (1 block): w-norm, exponents, bf16 B-fragments -> d_ws.
//  - main kernel: 256 thr / 8x32 tile / 1568 blocks; LDS 28.6 KB -> 5 blk/CU
//    (20 waves/CU). B-fragments streamed from L2 each K-step (shared across
//    all blocks), reused for 2 M-tiles.

#define H_ 224
#define W_ 224
#define C_ 32
#define F_ 32

#define NSTEP 18   // K = 288 = 18 * 16
#define HROWS 10   // staged halo rows (8 + 2)
#define HCOLS 34   // staged halo cols (32 + 2)

typedef __bf16 bf16_t;
typedef bf16_t bf16x8 __attribute__((ext_vector_type(8)));
typedef float f32x16 __attribute__((ext_vector_type(16)));

#define WFRAG_BYTES (NSTEP * 64 * 8 * 2)  // 18432 B

// ---------------- prep: w-norm + exponents + B-fragment swizzle -------------
__global__ __launch_bounds__(256) void cos2d_prep(
    const float* __restrict__ w, const float* __restrict__ p,
    const float* __restrict__ q, bf16_t* __restrict__ wfrag,
    float* __restrict__ winv, float* __restrict__ ef) {
  __shared__ float part[8][32];
  const int tid = threadIdx.x;
  const int f = tid & 31, kg = tid >> 5;  // 8 k-groups x 32 filters
  float s = 0.f;
#pragma unroll
  for (int i = 0; i < 36; ++i) {
    const float v = w[(kg + 8 * i) * F_ + f];
    s += v * v;
  }
  part[kg][f] = s;
  __syncthreads();
  if (tid < 32) {
    float t = 0.f;
#pragma unroll
    for (int g = 0; g < 8; ++g) t += part[g][tid];
    const float qt = q[0] * q[0] * 0.1f;
    winv[tid] = 1.f / (sqrtf(fmaxf(t, 1e-12f)) + qt);
    ef[tid] = p[tid] * p[tid] * 0.01f;
  }
  // B-fragment layout for mfma_f32_32x32x16_bf16:
  //   lane l holds col f = l&31, k = s2*16 + (l>>5)*8 + e  (e = 0..7).
  for (int t = tid; t < NSTEP * 64; t += 256) {
    const int s2 = t >> 6, l = t & 63;
    const int ff = l & 31;
    union { bf16_t v[8]; uint4 u; } tv;
#pragma unroll
    for (int e = 0; e < 8; ++e) {
      const int kk = s2 * 16 + ((l >> 5) << 3) + e;
      tv.v[e] = (bf16_t)w[kk * F_ + ff];
    }
    *(uint4*)(wfrag + (size_t)t * 8) = tv.u;
  }
}

// ---------------- main ------------------------------------------------------
__global__ __launch_bounds__(256, 5) void cos2d_main(
    const float* __restrict__ img, const bf16_t* __restrict__ wfrag,
    const float* __restrict__ winv, const float* __restrict__ ef,
    const float* __restrict__ q, float* __restrict__ out) {
  // stride 40 bf16 = 80 B per staged pixel: 16B-aligned; measured 0 bank
  // conflicts (round 2).
  __shared__ bf16_t xt[HROWS][HCOLS][40];
  __shared__ float ssum[HROWS][HCOLS];

  const int tid = threadIdx.x;
  const int lane = tid & 63;
  const int wv = tid >> 6;
  const int lp = lane & 31;

  const int bid = blockIdx.x;
  const int tw = bid % 7;
  const int th = (bid / 7) % 28;
  const int b  = bid / 196;
  const int h0 = th * 8, w0 = tw * 32;

  const float qt = q[0] * q[0] * 0.1f;
  const float efv = ef[lp];     // per-filter exponent (filter = lp)
  const float wnv = winv[lp];   // per-filter 1/(||w||+qt)

  // ---- stage image halo tile (rows h0-1..h0+8, cols w0-1..w0+32)
  for (int idx = tid; idx < HROWS * HCOLS; idx += 256) {
    const int rr = idx / HCOLS, cc = idx - rr * HCOLS;
    const int hh = h0 - 1 + rr, wc = w0 - 1 + cc;
    float s = 0.f;
    union { bf16_t v[32]; uint4 u[4]; } tv;
    if ((unsigned)hh < H_ && (unsigned)wc < W_) {
      const float4* p4 =
          (const float4*)(img + ((size_t)(b * H_ + hh) * W_ + wc) * C_);
#pragma unroll
      for (int jj = 0; jj < 8; ++jj) {
        const float4 v = p4[jj];
        s += v.x * v.x + v.y * v.y + v.z * v.z + v.w * v.w;
        tv.v[4 * jj + 0] = (bf16_t)v.x;
        tv.v[4 * jj + 1] = (bf16_t)v.y;
        tv.v[4 * jj + 2] = (bf16_t)v.z;
        tv.v[4 * jj + 3] = (bf16_t)v.w;
      }
    } else {
#pragma unroll
      for (int jj = 0; jj < 4; ++jj) tv.u[jj] = make_uint4(0u, 0u, 0u, 0u);
    }
    ssum[rr][cc] = s;
    uint4* dst = (uint4*)&xt[rr][cc][0];
#pragma unroll
    for (int jj = 0; jj < 4; ++jj) dst[jj] = tv.u[jj];
  }
  __syncthreads();

  const int mr0 = wv * 2;  // this wave's 2 output rows (tile-relative)

  // x_norm: 3x3 window sum of per-pixel channel sum-of-squares (fp32 exact)
  float xinv[2];
#pragma unroll
  for (int t = 0; t < 2; ++t) {
    const int mr = mr0 + t;
    const float xn2 = ssum[mr + 0][lp] + ssum[mr + 0][lp + 1] + ssum[mr + 0][lp + 2]
                    + ssum[mr + 1][lp] + ssum[mr + 1][lp + 1] + ssum[mr + 1][lp + 2]
                    + ssum[mr + 2][lp] + ssum[mr + 2][lp + 1] + ssum[mr + 2][lp + 2];
    xinv[t] = 1.f / (sqrtf(fmaxf(xn2, 1e-12f)) + qt);
  }

  f32x16 acc0, acc1;
#pragma unroll
  for (int i = 0; i < 16; ++i) { acc0[i] = 0.f; acc1[i] = 0.f; }

  // K loop: 18 steps of 16. A lane l -> pixel col = l&31, k = (l>>5)*8+e
  // (8 contiguous channels from LDS). B streamed from L2 (block-shared).
  const bf16x8* wf4 = (const bf16x8*)wfrag;
#pragma unroll
  for (int s2 = 0; s2 < NSTEP; ++s2) {
    const bf16x8 bf = wf4[s2 * 64 + lane];
    const int pos = s2 >> 1;
    const int dy = pos / 3, dx = pos - dy * 3;
    const int chof = (s2 & 1) * 16 + ((lane >> 5) << 3);
    const bf16x8 a0 = *(const bf16x8*)&xt[mr0 + 0 + dy][lp + dx][chof];
    const bf16x8 a1 = *(const bf16x8*)&xt[mr0 + 1 + dy][lp + dx][chof];
    acc0 = __builtin_amdgcn_mfma_f32_32x32x16_bf16(a0, bf, acc0, 0, 0, 0);
    acc1 = __builtin_amdgcn_mfma_f32_32x32x16_bf16(a1, bf, acc1, 0, 0, 0);
  }

  // epilogue: C/D layout col = lane&31 (filter), row = (j&3)+8*(j>>2)+4*(lane>>5)
#pragma unroll
  for (int t = 0; t < 2; ++t) {
    const f32x16& acc = t ? acc1 : acc0;
    const int obase = (b * H_ + h0 + mr0 + t) * W_ + w0;
#pragma unroll
    for (int jj = 0; jj < 16; ++jj) {
      const int row = (jj & 3) + 8 * (jj >> 2) + 4 * (lane >> 5);
      const float xi = __shfl(xinv[t], row);  // xinv of pixel-col `row`
      const float sim = acc[jj] * xi * wnv;
      const float ps = fabsf(sim) + 1e-12f;
      float r = exp2f(efv * __log2f(ps));
      r = copysignf(r, sim);
      out[(size_t)(obase + row) * F_ + lp] = r;
    }
  }
}

// ---------------- launch ----------------------------------------------------
extern "C" void kernel_launch(void* const* d_in, const int* in_sizes, int n_in,
                              void* d_out, int out_size, void* d_ws, size_t ws_size,
                              hipStream_t stream) {
  const float* img = (const float*)d_in[0];
  const float* w   = (const float*)d_in[1];
  const float* p   = (const float*)d_in[2];
  const float* q   = (const float*)d_in[3];

  bf16_t* wfrag = (bf16_t*)d_ws;
  float*  winv  = (float*)((char*)d_ws + WFRAG_BYTES);
  float*  ef    = winv + 64;

  cos2d_prep<<<1, 256, 0, stream>>>(w, p, q, wfrag, winv, ef);
  // 8 images * 28 row-tiles * 7 col-tiles = 1568 blocks, 256 threads (4 waves)
  cos2d_main<<<1568, 256, 0, stream>>>(img, wfrag, winv, ef, q, (float*)d_out);
}